// Round 13
// baseline (369.217 us; speedup 1.0000x reference)
//
#include <hip/hip_runtime.h>
#include <math.h>

typedef __attribute__((ext_vector_type(8))) short short8;
typedef __attribute__((ext_vector_type(4))) short short4v;
typedef __attribute__((ext_vector_type(4))) float f32x4;

#define NB 256
#define NVU 64
#define NTU 77
#define PD 512

// ---- d_out offsets (in floats) ----
#define O_VP 3ull
#define O_TP (O_VP + (size_t)NB * NVU * PD)
#define O_VG (O_TP + (size_t)NB * NTU * PD)
#define O_TG (O_VG + (size_t)NB * PD)
#define O_SM (O_TG + (size_t)NB * PD)

// ---- ws offsets (bytes) ----
#define WS_VW1T 0u
#define WS_VW2T 524288u
#define WS_TW1T 1048576u
#define WS_TW2T 1572864u
#define WS_GVWT 2097152u
#define WS_GTWT 2883584u
#define WS_LOG  3552256u
#define WS_DIAG 3814400u
#define WS_RLSE 3815424u
#define WS_CLSE 3816448u
#define WS_UP   3817472u
#define WS_UC   3818496u
#define WS_PART 3819520u   // 512 floats

__device__ inline short f2bf(float f) {
  union { float f; unsigned u; } v; v.f = f;
  unsigned r = v.u + 0x7FFFu + ((v.u >> 16) & 1u);   // RNE
  return (short)(r >> 16);
}
__device__ inline float bf2f(short s) {
  union { unsigned u; float f; } v; v.u = ((unsigned)(unsigned short)s) << 16;
  return v.f;
}

__device__ inline float blk_sum_(float x, float* buf, int nw) {
  const int lane = threadIdx.x & 63, w = threadIdx.x >> 6;
  #pragma unroll
  for (int m = 1; m < 64; m <<= 1) x += __shfl_xor(x, m, 64);
  __syncthreads();
  if (lane == 0) buf[w] = x;
  __syncthreads();
  float s = 0.f;
  for (int i = 0; i < nw; ++i) s += buf[i];
  return s;
}
__device__ inline float blk_max_(float x, float* buf, int nw) {
  const int lane = threadIdx.x & 63, w = threadIdx.x >> 6;
  #pragma unroll
  for (int m = 1; m < 64; m <<= 1) x = fmaxf(x, __shfl_xor(x, m, 64));
  __syncthreads();
  if (lane == 0) buf[w] = x;
  __syncthreads();
  float s = buf[0];
  for (int i = 1; i < nw; ++i) s = fmaxf(s, buf[i]);
  return s;
}

// ---------------- prep: 4 unit weights [512][512] fp32 -> fragment-major SWIZZLED bf16 ----
// chunk kc (32 k's): pos = n*32 + ((s ^ ((n>>1)&3))<<3) + j, where k%32 = s*8+j.
__global__ __launch_bounds__(256) void k_cvt_frag4(
    const float* __restrict__ s0, const float* __restrict__ s1,
    const float* __restrict__ s2, const float* __restrict__ s3,
    short* __restrict__ d0, short* __restrict__ d1,
    short* __restrict__ d2, short* __restrict__ d3) {
  int m = blockIdx.x >> 10;
  const float* src = m == 0 ? s0 : m == 1 ? s1 : m == 2 ? s2 : s3;
  short* dst = m == 0 ? d0 : m == 1 ? d1 : m == 2 ? d2 : d3;
  int idx = (blockIdx.x & 1023) * 256 + threadIdx.x;   // k*512 + n (coalesced read)
  int k = idx >> 9, n = idx & 511;
  int kc = k >> 5, t = k & 31;
  int s = t >> 3, j = t & 7;
  int sw = (s ^ ((n >> 1) & 3)) << 3;
  dst[(size_t)kc * 16384 + n * 32 + sw + j] = f2bf(src[idx]);
}

// ---------------- prep: global-proj weights [K][512] -> [512][K] bf16 ----------------
__global__ __launch_bounds__(256) void k_transpose2(
    const float* __restrict__ gv, short* __restrict__ dv_,
    const float* __restrict__ gt, short* __restrict__ dt_) {
  int bid = blockIdx.x;
  if (bid < 1536) {
    int idx = bid * 256 + threadIdx.x;      // 768*512
    int k = idx >> 9, n = idx & 511;
    dv_[(size_t)n * 768 + k] = f2bf(gv[idx]);
  } else {
    int idx = (bid - 1536) * 256 + threadIdx.x;  // 512*512
    int k = idx >> 9, n = idx & 511;
    dt_[(size_t)n * 512 + k] = f2bf(gt[idx]);
  }
}

// ---------------- fused unit MLP: 128-row tiles, reg-prefetch single-buf B, nt I/O ----------------
// 282 blocks = 128 vis + 154 txt. 16 waves = 4rg x 4cg, wave = 32 rows x 128 cols.
// LDS: As 131072 (swizzled, unpadded) + Bs 32768 = 163840 B (red bufs aliased in Bs).
// __launch_bounds__(1024, 4): 4 waves/EU = 1 block/CU -> 128-VGPR budget (no spills).
__global__ __launch_bounds__(1024, 4) void k_unit_mlp9(
    const float* __restrict__ Xv, const float* __restrict__ Xt,
    const short* __restrict__ vWf1, const float* __restrict__ vb1,
    const float* __restrict__ vg, const float* __restrict__ vbt,
    const short* __restrict__ vWf2, const float* __restrict__ vb2,
    const short* __restrict__ tWf1, const float* __restrict__ tb1,
    const float* __restrict__ tg, const float* __restrict__ tbt,
    const short* __restrict__ tWf2, const float* __restrict__ tb2,
    float* __restrict__ outV, float* __restrict__ outT) {
  __shared__ __align__(16) short As[65536];   // 131072 B: 128 rows x 64 slots x short8
  __shared__ __align__(16) short Bs[16384];   // 32768 B: one weight chunk / red bufs
  float* redS = (float*)Bs;                   // [4][128] aliased (between GEMMs only)
  float* redQ = (float*)(Bs + 4096);          // [4][128]

  const int tid = threadIdx.x;
  const int w = tid >> 6, lane = tid & 63;
  const int rg = w >> 2, cg = w & 3;          // 4 row-groups (32 rows) x 4 col-groups (128 cols)
  const int hi = lane >> 4, lo = lane & 15;

  // bijective XCD swizzle for 282 = 8*35 + 2
  const int xcd = blockIdx.x & 7, ii = blockIdx.x >> 3;
  const int orig = (xcd < 2 ? xcd * 36 : 72 + (xcd - 2) * 35) + ii;
  const bool isv = orig < 128;
  const int rb = isv ? orig : orig - 128;
  const float* __restrict__ X   = isv ? Xv : Xt;
  const short* __restrict__ Wf1 = isv ? vWf1 : tWf1;
  const float* __restrict__ b1  = isv ? vb1  : tb1;
  const float* __restrict__ gg  = isv ? vg   : tg;
  const float* __restrict__ bt  = isv ? vbt  : tbt;
  const short* __restrict__ Wf2 = isv ? vWf2 : tWf2;
  const float* __restrict__ b2  = isv ? vb2  : tb2;
  float* __restrict__ outF      = isv ? outV : outT;
  const size_t row0 = (size_t)rb * 128;

  // conflict-free swizzled B-frag read base (matches baked weight swizzle)
  const int bswz = (cg * 128 + lo) * 32 + ((hi ^ ((lo >> 1) & 3)) * 8);
  const int ar0 = rg * 32 + lo, ar1 = ar0 + 16;
  const int rx = lo & 7;                       // A slot-XOR (row&7; same for ar0/ar1)

  // ---- reg-prefetch W1 chunk 0 (32B/thread) ----
  short8 q0 = *(const short8*)(Wf1 + tid * 16);
  short8 q1 = *(const short8*)(Wf1 + tid * 16 + 8);

  // ---- stage X tile (128x512) -> As bf16, slot-swizzled (nt loads) ----
  #pragma unroll
  for (int i = 0; i < 8; ++i) {
    int L = i * 1024 + tid;                    // 8192 slots = 128 rows x 64
    int row = L >> 6, slot = L & 63;
    const f32x4* xp = (const f32x4*)(X + (row0 + row) * 512 + slot * 8);
    f32x4 f0 = __builtin_nontemporal_load(xp);
    f32x4 f1 = __builtin_nontemporal_load(xp + 1);
    short8 s8 = {f2bf(f0[0]), f2bf(f0[1]), f2bf(f0[2]), f2bf(f0[3]),
                 f2bf(f1[0]), f2bf(f1[1]), f2bf(f1[2]), f2bf(f1[3])};
    *(short8*)&As[row * 512 + ((slot ^ (row & 7)) << 3)] = s8;
  }
  *(short8*)&Bs[tid * 16] = q0;
  *(short8*)&Bs[tid * 16 + 8] = q1;
  __syncthreads();

  f32x4 acc[2][8];
  #pragma unroll
  for (int rt = 0; rt < 2; ++rt)
    #pragma unroll
    for (int ct = 0; ct < 8; ++ct)
      acc[rt][ct] = (f32x4){0.f, 0.f, 0.f, 0.f};

  // ---- GEMM1 ----
  for (int kc = 0; kc < 16; ++kc) {
    if (kc < 15) {
      const short* wp = Wf1 + (size_t)(kc + 1) * 16384 + tid * 16;
      q0 = *(const short8*)(wp);
      q1 = *(const short8*)(wp + 8);
    }
    int aslot = ((kc * 4 + hi) ^ rx) << 3;
    short8 a0 = *(const short8*)&As[ar0 * 512 + aslot];
    short8 a1 = *(const short8*)&As[ar1 * 512 + aslot];
    #pragma unroll
    for (int ct = 0; ct < 8; ++ct) {
      short8 bb = *(const short8*)&Bs[bswz + ct * 512];
      acc[0][ct] = __builtin_amdgcn_mfma_f32_16x16x32_bf16(a0, bb, acc[0][ct], 0, 0, 0);
      acc[1][ct] = __builtin_amdgcn_mfma_f32_16x16x32_bf16(a1, bb, acc[1][ct], 0, 0, 0);
    }
    __syncthreads();                          // all reads of chunk kc done
    if (kc < 15) {
      *(short8*)&Bs[tid * 16] = q0;
      *(short8*)&Bs[tid * 16 + 8] = q1;
      __syncthreads();                        // next chunk visible
    }
  }

  // reg-prefetch W2 chunk 0 (hidden under LN phase)
  q0 = *(const short8*)(Wf2 + tid * 16);
  q1 = *(const short8*)(Wf2 + tid * 16 + 8);

  // ---- bias + LN reduction (red bufs alias Bs; GEMM1 reads are done) ----
  {
    float ps[2][4], pq[2][4];
    #pragma unroll
    for (int rt = 0; rt < 2; ++rt)
      #pragma unroll
      for (int r = 0; r < 4; ++r) { ps[rt][r] = 0.f; pq[rt][r] = 0.f; }
    #pragma unroll
    for (int ct = 0; ct < 8; ++ct) {
      float bia = b1[cg * 128 + ct * 16 + lo];
      #pragma unroll
      for (int rt = 0; rt < 2; ++rt)
        #pragma unroll
        for (int r = 0; r < 4; ++r) {
          float v = acc[rt][ct][r] + bia;
          acc[rt][ct][r] = v;
          ps[rt][r] += v; pq[rt][r] += v * v;
        }
    }
    #pragma unroll
    for (int m = 1; m < 16; m <<= 1)
      #pragma unroll
      for (int rt = 0; rt < 2; ++rt)
        #pragma unroll
        for (int r = 0; r < 4; ++r) {
          ps[rt][r] += __shfl_xor(ps[rt][r], m, 64);
          pq[rt][r] += __shfl_xor(pq[rt][r], m, 64);
        }
    if (lo == 0) {
      #pragma unroll
      for (int rt = 0; rt < 2; ++rt)
        #pragma unroll
        for (int r = 0; r < 4; ++r) {
          int rr = rg * 32 + rt * 16 + hi * 4 + r;
          redS[cg * 128 + rr] = ps[rt][r];
          redQ[cg * 128 + rr] = pq[rt][r];
        }
    }
  }
  __syncthreads();

  // ---- LN + GELU -> As (swizzled H tile) ----
  #pragma unroll
  for (int rt = 0; rt < 2; ++rt) {
    float mu[4], rs[4];
    #pragma unroll
    for (int r = 0; r < 4; ++r) {
      int rr = rg * 32 + rt * 16 + hi * 4 + r;
      float s = redS[rr] + redS[128 + rr] + redS[256 + rr] + redS[384 + rr];
      float q = redQ[rr] + redQ[128 + rr] + redQ[256 + rr] + redQ[384 + rr];
      float m_ = s * (1.f / 512.f);
      mu[r] = m_;
      rs[r] = rsqrtf(q * (1.f / 512.f) - m_ * m_ + 1e-5f);
    }
    #pragma unroll
    for (int ct = 0; ct < 8; ++ct) {
      int col = cg * 128 + ct * 16 + lo;
      float ga = gg[col], be = bt[col];
      #pragma unroll
      for (int r = 0; r < 4; ++r) {
        int rr = rg * 32 + rt * 16 + hi * 4 + r;
        float xn = (acc[rt][ct][r] - mu[r]) * rs[r] * ga + be;
        float ge = 0.5f * xn * (1.f + erff(xn * 0.70710678118654752f));
        As[rr * 512 + (((col >> 3) ^ (rr & 7)) << 3) + (col & 7)] = f2bf(ge);
      }
    }
  }
  __syncthreads();                             // red reads + H writes done
  *(short8*)&Bs[tid * 16] = q0;                // stage W2 chunk 0
  *(short8*)&Bs[tid * 16 + 8] = q1;
  __syncthreads();

  // ---- GEMM2 ----
  #pragma unroll
  for (int rt = 0; rt < 2; ++rt)
    #pragma unroll
    for (int ct = 0; ct < 8; ++ct)
      acc[rt][ct] = (f32x4){0.f, 0.f, 0.f, 0.f};
  for (int kc = 0; kc < 16; ++kc) {
    if (kc < 15) {
      const short* wp = Wf2 + (size_t)(kc + 1) * 16384 + tid * 16;
      q0 = *(const short8*)(wp);
      q1 = *(const short8*)(wp + 8);
    }
    int aslot = ((kc * 4 + hi) ^ rx) << 3;
    short8 a0 = *(const short8*)&As[ar0 * 512 + aslot];
    short8 a1 = *(const short8*)&As[ar1 * 512 + aslot];
    #pragma unroll
    for (int ct = 0; ct < 8; ++ct) {
      short8 bb = *(const short8*)&Bs[bswz + ct * 512];
      acc[0][ct] = __builtin_amdgcn_mfma_f32_16x16x32_bf16(a0, bb, acc[0][ct], 0, 0, 0);
      acc[1][ct] = __builtin_amdgcn_mfma_f32_16x16x32_bf16(a1, bb, acc[1][ct], 0, 0, 0);
    }
    __syncthreads();
    if (kc < 15) {
      *(short8*)&Bs[tid * 16] = q0;
      *(short8*)&Bs[tid * 16 + 8] = q1;
      __syncthreads();
    }
  }

  // ---- bias2 + row L2 norm (redQ aliases Bs; GEMM2 reads done) ----
  {
    float pq[2][4];
    #pragma unroll
    for (int rt = 0; rt < 2; ++rt)
      #pragma unroll
      for (int r = 0; r < 4; ++r) pq[rt][r] = 0.f;
    #pragma unroll
    for (int ct = 0; ct < 8; ++ct) {
      float bia = b2[cg * 128 + ct * 16 + lo];
      #pragma unroll
      for (int rt = 0; rt < 2; ++rt)
        #pragma unroll
        for (int r = 0; r < 4; ++r) {
          float v = acc[rt][ct][r] + bia;
          acc[rt][ct][r] = v;
          pq[rt][r] += v * v;
        }
    }
    #pragma unroll
    for (int m = 1; m < 16; m <<= 1)
      #pragma unroll
      for (int rt = 0; rt < 2; ++rt)
        #pragma unroll
        for (int r = 0; r < 4; ++r) pq[rt][r] += __shfl_xor(pq[rt][r], m, 64);
    if (lo == 0) {
      #pragma unroll
      for (int rt = 0; rt < 2; ++rt)
        #pragma unroll
        for (int r = 0; r < 4; ++r)
          redQ[cg * 128 + rg * 32 + rt * 16 + hi * 4 + r] = pq[rt][r];
    }
  }
  __syncthreads();
  #pragma unroll
  for (int rt = 0; rt < 2; ++rt) {
    float invn[4];
    #pragma unroll
    for (int r = 0; r < 4; ++r) {
      int rr = rg * 32 + rt * 16 + hi * 4 + r;
      float q = redQ[rr] + redQ[128 + rr] + redQ[256 + rr] + redQ[384 + rr];
      invn[r] = 1.f / fmaxf(sqrtf(q), 1e-12f);
    }
    #pragma unroll
    for (int ct = 0; ct < 8; ++ct) {
      int col = cg * 128 + ct * 16 + lo;
      #pragma unroll
      for (int r = 0; r < 4; ++r) {
        float* op = outF + (row0 + rg * 32 + rt * 16 + hi * 4 + r) * 512 + col;
        __builtin_nontemporal_store(acc[rt][ct][r] * invn[r], op);
      }
    }
  }
}

// ---------------- global projections (both), Linear -> LN -> l2norm ----------------
__global__ __launch_bounds__(256) void k_gproj2(
    const float* __restrict__ vsrc, const float* __restrict__ tsrc,
    const short* __restrict__ vWT, const float* __restrict__ vbias,
    const float* __restrict__ vgg, const float* __restrict__ vbt,
    const short* __restrict__ tWT, const float* __restrict__ tbias,
    const float* __restrict__ tgg, const float* __restrict__ tbt,
    float* __restrict__ outV, float* __restrict__ outT) {
  __shared__ float srow[768];
  __shared__ float rbuf[4];
  const bool isv = blockIdx.x < 256;
  const int row = blockIdx.x & 255, tid = threadIdx.x;
  const int K = isv ? 768 : 512;
  const float* src = isv ? vsrc : tsrc;
  const short* WT = isv ? vWT : tWT;
  const float* bias = isv ? vbias : tbias;
  const float* gg = isv ? vgg : tgg;
  const float* bt = isv ? vbt : tbt;
  float* outp = isv ? outV : outT;

  for (int k = tid; k < K; k += 256) srow[k] = src[(size_t)row * K + k];
  __syncthreads();
  float v0 = 0.f, v1 = 0.f;
  const short* wp0 = WT + (size_t)tid * K;
  const short* wp1 = WT + (size_t)(tid + 256) * K;
  for (int k = 0; k < K; k += 8) {
    short8 wa = *(const short8*)(wp0 + k);
    short8 wb = *(const short8*)(wp1 + k);
    #pragma unroll
    for (int j = 0; j < 8; ++j) {
      float sv = srow[k + j];
      v0 += sv * bf2f(wa[j]);
      v1 += sv * bf2f(wb[j]);
    }
  }
  v0 += bias[tid]; v1 += bias[tid + 256];
  float s = blk_sum_(v0 + v1, rbuf, 4);
  float q = blk_sum_(v0 * v0 + v1 * v1, rbuf, 4);
  float mu = s * (1.f / 512.f);
  float var = q * (1.f / 512.f) - mu * mu;
  float rs = rsqrtf(var + 1e-5f);
  float y0 = (v0 - mu) * rs * gg[tid] + bt[tid];
  float y1 = (v1 - mu) * rs * gg[tid + 256] + bt[tid + 256];
  float ss = blk_sum_(y0 * y0 + y1 * y1, rbuf, 4);
  float invn = 1.f / fmaxf(sqrtf(ss), 1e-12f);
  outp[(size_t)row * 512 + tid] = y0 * invn;
  outp[(size_t)row * 512 + tid + 256] = y1 * invn;
}

// ---------------- logits rows ----------------
__global__ __launch_bounds__(256) void k_logits_row(
    const float* __restrict__ vgp, const float* __restrict__ tgp,
    const float* __restrict__ lsc, float* __restrict__ logits,
    float* __restrict__ diag, float* __restrict__ rlse) {
  __shared__ __align__(16) float vrow[512];
  __shared__ float rbuf[4];
  const int i = blockIdx.x, tid = threadIdx.x;
  const float scale = fminf(expf(lsc[0]), 100.f);
  vrow[tid] = vgp[(size_t)i * 512 + tid];
  vrow[tid + 256] = vgp[(size_t)i * 512 + 256 + tid];
  __syncthreads();
  const float4* tp4 = (const float4*)(tgp + (size_t)tid * 512);
  const float4* v4 = (const float4*)vrow;
  float s = 0.f;
  for (int k = 0; k < 128; ++k) {
    float4 t = tp4[k], vv = v4[k];
    s += t.x * vv.x + t.y * vv.y + t.z * vv.z + t.w * vv.w;
  }
  float lg = scale * s;
  logits[(size_t)i * 256 + tid] = lg;
  if (tid == i) diag[i] = lg;
  float mx = blk_max_(lg, rbuf, 4);
  float se = blk_sum_(expf(lg - mx), rbuf, 4);
  if (tid == 0) rlse[i] = mx + logf(se);
}

// ---------------- logits cols ----------------
__global__ __launch_bounds__(256) void k_logits_col(
    const float* __restrict__ logits, float* __restrict__ clse) {
  __shared__ float rbuf[4];
  const int j = blockIdx.x, tid = threadIdx.x;
  float lg = logits[(size_t)tid * 256 + j];
  float mx = blk_max_(lg, rbuf, 4);
  float se = blk_sum_(expf(lg - mx), rbuf, 4);
  if (tid == 0) clse[j] = mx + logf(se);
}

// ---------------- per-batch sim + mutual-NN unit loss (512 thr, K-split) ----------------
__global__ __launch_bounds__(512) void k_unit_sim(
    const float* __restrict__ vpp, const float* __restrict__ tpp,
    const float* __restrict__ lsc, float* __restrict__ simout,
    float* __restrict__ up, float* __restrict__ uc) {
  __shared__ float Sp[2][64][81];
  __shared__ float lse_r[64];
  __shared__ int bestt[64];
  __shared__ float lse_c[80];
  __shared__ int bestv[80];
  __shared__ float rbuf[8];
  const int b = blockIdx.x;
  const int tid = threadIdx.x;
  const int w = tid >> 6, lane = tid & 63;
  const int wq = w >> 1, kg = w & 1;       // v-row group, k-half
  const int hi = lane >> 4, lo = lane & 15;
  const float scale = fminf(expf(lsc[0]), 100.f);

  f32x4 acc[5];
  #pragma unroll
  for (int ct = 0; ct < 5; ++ct) acc[ct] = (f32x4){0.f, 0.f, 0.f, 0.f};

  const float* va = vpp + ((size_t)b * 64 + wq * 16 + lo) * 512 + kg * 256;
  const float* tbase = tpp + (size_t)b * 77 * 512 + kg * 256;
  for (int k0 = 0; k0 < 256; k0 += 32) {
    float4 f0 = *(const float4*)(va + k0 + hi * 8);
    float4 f1 = *(const float4*)(va + k0 + hi * 8 + 4);
    short8 a = {f2bf(f0.x), f2bf(f0.y), f2bf(f0.z), f2bf(f0.w),
                f2bf(f1.x), f2bf(f1.y), f2bf(f1.z), f2bf(f1.w)};
    #pragma unroll
    for (int ct = 0; ct < 5; ++ct) {
      int rj = ct * 16 + lo;
      short8 bb = {0, 0, 0, 0, 0, 0, 0, 0};
      if (rj < 77) {
        const float* tb = tbase + (size_t)rj * 512 + k0 + hi * 8;
        float4 g0 = *(const float4*)tb;
        float4 g1 = *(const float4*)(tb + 4);
        bb = (short8){f2bf(g0.x), f2bf(g0.y), f2bf(g0.z), f2bf(g0.w),
                      f2bf(g1.x), f2bf(g1.y), f2bf(g1.z), f2bf(g1.w)};
      }
      acc[ct] = __builtin_amdgcn_mfma_f32_16x16x32_bf16(a, bb, acc[ct], 0, 0, 0);
    }
  }
  #pragma unroll
  for (int ct = 0; ct < 5; ++ct)
    #pragma unroll
    for (int r = 0; r < 4; ++r) {
      int i = wq * 16 + hi * 4 + r, j = ct * 16 + lo;
      if (j < 77) Sp[kg][i][j] = acc[ct][r];
    }
  __syncthreads();
  for (int idx = tid; idx < 64 * 77; idx += 512) {
    int i = idx / 77, j = idx - i * 77;
    float s = Sp[0][i][j] + Sp[1][i][j];
    simout[((size_t)b * 64 + i) * 77 + j] = s;
    Sp[0][i][j] = s * scale;
  }
  __syncthreads();
  if (tid < 64) {
    float mx = -1e30f; int am = 0;
    for (int t = 0; t < 77; ++t) { float x = Sp[0][tid][t]; if (x > mx) { mx = x; am = t; } }
    float se = 0.f;
    for (int t = 0; t < 77; ++t) se += expf(Sp[0][tid][t] - mx);
    lse_r[tid] = mx + logf(se); bestt[tid] = am;
  } else if (tid < 64 + 77) {
    int t = tid - 64;
    float mx = -1e30f; int am = 0;
    for (int v = 0; v < 64; ++v) { float x = Sp[0][v][t]; if (x > mx) { mx = x; am = v; } }
    float se = 0.f;
    for (int v = 0; v < 64; ++v) se += expf(Sp[0][v][t] - mx);
    lse_c[t] = mx + logf(se); bestv[t] = am;
  }
  __syncthreads();
  float c = 0.f, cnt = 0.f;
  if (tid < 64) {
    int j = bestt[tid];
    if (bestv[j] == tid) {
      float sv = Sp[0][tid][j];
      c = -((sv - lse_r[tid]) + (sv - lse_c[j]));
      cnt = 2.f;
    }
  }
  c = blk_sum_(c, rbuf, 8);
  cnt = blk_sum_(cnt, rbuf, 8);
  if (tid == 0) { up[b] = c; uc[b] = cnt; }
}

// ---------------- fused diversity (both modalities): LDS-staged gram, norms from diag ----------------
__global__ __launch_bounds__(320) void k_div2(
    const float* __restrict__ Xv, const float* __restrict__ Xt,
    float* __restrict__ part) {
  __shared__ __align__(16) short Bsd[80][136];
  __shared__ float invs[80];
  __shared__ float rbuf[5];
  const int bid = blockIdx.x;
  const bool isv = bid < 256;
  const int b = bid & 255;
  const int N = isv ? 64 : 77;
  const float* X = (isv ? Xv : Xt) + (size_t)b * N * 512;
  const int w = threadIdx.x >> 6, lane = threadIdx.x & 63;
  const int hi = lane >> 4, lo = lane & 15;
  const int ri = w * 16 + lo;

  f32x4 acc[5];
  #pragma unroll
  for (int ct = 0; ct < 5; ++ct) acc[ct] = (f32x4){0.f, 0.f, 0.f, 0.f};

  for (int c = 0; c < 4; ++c) {
    for (int s = threadIdx.x; s < 80 * 32; s += 320) {
      int r = s >> 5, cgp = s & 31;
      short4v s4 = {0, 0, 0, 0};
      if (r < N) {
        float4 f = *(const float4*)(X + (size_t)r * 512 + c * 128 + cgp * 4);
        s4 = (short4v){f2bf(f.x), f2bf(f.y), f2bf(f.z), f2bf(f.w)};
      }
      *(short4v*)&Bsd[r][cgp * 4] = s4;
    }
    __syncthreads();
    #pragma unroll
    for (int kc = 0; kc < 4; ++kc) {
      short8 a = *(const short8*)&Bsd[ri][kc * 32 + hi * 8];
      #pragma unroll
      for (int ct = 0; ct < 5; ++ct) {
        short8 bb = *(const short8*)&Bsd[ct * 16 + lo][kc * 32 + hi * 8];
        acc[ct] = __builtin_amdgcn_mfma_f32_16x16x32_bf16(a, bb, acc[ct], 0, 0, 0);
      }
    }
    __syncthreads();
  }

  #pragma unroll
  for (int ct = 0; ct < 5; ++ct)
    #pragma unroll
    for (int r = 0; r < 4; ++r) {
      int i = w * 16 + hi * 4 + r, j = ct * 16 + lo;
      if (i == j && i < N) invs[i] = 1.f / fmaxf(sqrtf(fmaxf(acc[ct][r], 0.f)), 1e-12f);
    }
  __syncthreads();

  float cs = 0.f;
  #pragma unroll
  for (int ct = 0; ct < 5; ++ct)
    #pragma unroll
    for (int r = 0; r < 4; ++r) {
      int i = w * 16 + hi * 4 + r, j = ct * 16 + lo;
      if (i < N && j < N && i != j)
        cs += fabsf(acc[ct][r]) * invs[i] * invs[j];
    }
  #pragma unroll
  for (int m = 1; m < 64; m <<= 1) cs += __shfl_xor(cs, m, 64);
  if (lane == 0) rbuf[w] = cs;
  __syncthreads();
  if (threadIdx.x == 0) {
    float s = 0.f;
    for (int i = 0; i < 5; ++i) s += rbuf[i];
    part[bid] = s;
  }
}

// ---------------- final scalar losses ----------------
__global__ __launch_bounds__(256) void k_final(
    const float* __restrict__ diag, const float* __restrict__ rlse,
    const float* __restrict__ clse, const float* __restrict__ up,
    const float* __restrict__ uc, const float* __restrict__ part,
    float* __restrict__ out) {
  __shared__ float rbuf[4];
  const int tid = threadIdx.x;
  float d = diag[tid];
  float s1 = blk_sum_(d - rlse[tid], rbuf, 4);
  float s2 = blk_sum_(d - clse[tid], rbuf, 4);
  float su = blk_sum_(up[tid], rbuf, 4);
  float sc = blk_sum_(uc[tid], rbuf, 4);
  float sv = blk_sum_(part[tid], rbuf, 4);
  float st = blk_sum_(part[tid + 256], rbuf, 4);
  if (tid == 0) {
    out[0] = -(s1 * (1.f / 256.f) + s2 * (1.f / 256.f)) * 0.5f;
    out[1] = su / fmaxf(sc, 1.f);
    out[2] = (sv / (256.f * 64.f * 63.f) + st / (256.f * 77.f * 76.f)) * 0.5f;
  }
}

extern "C" void kernel_launch(void* const* d_in, const int* in_sizes, int n_in,
                              void* d_out, int out_size, void* d_ws, size_t ws_size,
                              hipStream_t stream) {
  const float* vis_units = (const float*)d_in[0];
  const float* txt_units = (const float*)d_in[1];
  const float* vis_cls = (const float*)d_in[2];
  const float* txt_cls = (const float*)d_in[3];
  const float* vW1 = (const float*)d_in[4];
  const float* vb1 = (const float*)d_in[5];
  const float* vg  = (const float*)d_in[6];
  const float* vbt = (const float*)d_in[7];
  const float* vW2 = (const float*)d_in[8];
  const float* vb2 = (const float*)d_in[9];
  const float* tW1 = (const float*)d_in[10];
  const float* tb1 = (const float*)d_in[11];
  const float* tg  = (const float*)d_in[12];
  const float* tbt = (const float*)d_in[13];
  const float* tW2 = (const float*)d_in[14];
  const float* tb2 = (const float*)d_in[15];
  const float* gvW = (const float*)d_in[16];
  const float* gvb = (const float*)d_in[17];
  const float* gvg = (const float*)d_in[18];
  const float* gvbt = (const float*)d_in[19];
  const float* gtW = (const float*)d_in[20];
  const float* gtb = (const float*)d_in[21];
  const float* gtg = (const float*)d_in[22];
  const float* gtbt = (const float*)d_in[23];
  const float* lsc = (const float*)d_in[24];

  float* out = (float*)d_out;
  char* ws = (char*)d_ws;
  short* vW1T = (short*)(ws + WS_VW1T);
  short* vW2T = (short*)(ws + WS_VW2T);
  short* tW1T = (short*)(ws + WS_TW1T);
  short* tW2T = (short*)(ws + WS_TW2T);
  short* gvWT = (short*)(ws + WS_GVWT);
  short* gtWT = (short*)(ws + WS_GTWT);
  float* logits = (float*)(ws + WS_LOG);
  float* diag = (float*)(ws + WS_DIAG);
  float* rlse = (float*)(ws + WS_RLSE);
  float* clse = (float*)(ws + WS_CLSE);
  float* up = (float*)(ws + WS_UP);
  float* uc = (float*)(ws + WS_UC);
  float* part = (float*)(ws + WS_PART);

  // prep (swizzle baked into unit-weight layout)
  k_cvt_frag4<<<4096, 256, 0, stream>>>(vW1, vW2, tW1, tW2, vW1T, vW2T, tW1T, tW2T);
  k_transpose2<<<2560, 256, 0, stream>>>(gvW, gvWT, gtW, gtWT);

  // unit MLPs (128-row tiles, reg-prefetch B, nt I/O, 128-VGPR budget)
  k_unit_mlp9<<<282, 1024, 0, stream>>>(
      vis_units, txt_units,
      vW1T, vb1, vg, vbt, vW2T, vb2,
      tW1T, tb1, tg, tbt, tW2T, tb2,
      out + O_VP, out + O_TP);

  // global projections
  k_gproj2<<<512, 256, 0, stream>>>(vis_cls, txt_cls,
      gvWT, gvb, gvg, gvbt, gtWT, gtb, gtg, gtbt,
      out + O_VG, out + O_TG);

  // global CLIP loss pieces
  k_logits_row<<<256, 256, 0, stream>>>(out + O_VG, out + O_TG, lsc, logits, diag, rlse);
  k_logits_col<<<256, 256, 0, stream>>>(logits, clse);

  // unit sim + mutual-NN loss partials (+ sim_matrix output)
  k_unit_sim<<<256, 512, 0, stream>>>(out + O_VP, out + O_TP, lsc, out + O_SM, up, uc);

  // diversity (both modalities)
  k_div2<<<512, 320, 0, stream>>>(vis_units, txt_units, part);

  // final scalars
  k_final<<<1, 256, 0, stream>>>(diag, rlse, clse, up, uc, part, out);

  (void)in_sizes; (void)n_in; (void)out_size; (void)ws_size;
}

// Round 14
// 274.544 us; speedup vs baseline: 1.3448x; 1.3448x over previous
//
#include <hip/hip_runtime.h>
#include <math.h>

typedef __attribute__((ext_vector_type(8))) short short8;
typedef __attribute__((ext_vector_type(4))) short short4v;
typedef __attribute__((ext_vector_type(4))) float f32x4;

#define NB 256
#define NVU 64
#define NTU 77
#define PD 512

// ---- d_out offsets (in floats) ----
#define O_VP 3ull
#define O_TP (O_VP + (size_t)NB * NVU * PD)
#define O_VG (O_TP + (size_t)NB * NTU * PD)
#define O_TG (O_VG + (size_t)NB * PD)
#define O_SM (O_TG + (size_t)NB * PD)

// ---- ws offsets (bytes) ----
#define WS_VW1T 0u
#define WS_VW2T 524288u
#define WS_TW1T 1048576u
#define WS_TW2T 1572864u
#define WS_GVWT 2097152u
#define WS_GTWT 2883584u
#define WS_LOG  3552256u
#define WS_DIAG 3814400u
#define WS_RLSE 3815424u
#define WS_CLSE 3816448u
#define WS_UP   3817472u
#define WS_UC   3818496u
#define WS_PART 3819520u   // 512 floats

// async global->LDS, 16B per lane; LDS dest = wave-uniform base + lane*16
#define GL_LDS16(gp, lp) __builtin_amdgcn_global_load_lds( \
    (const __attribute__((address_space(1))) void*)(gp), \
    (__attribute__((address_space(3))) void*)(lp), 16, 0, 0)

__device__ inline short f2bf(float f) {
  union { float f; unsigned u; } v; v.f = f;
  unsigned r = v.u + 0x7FFFu + ((v.u >> 16) & 1u);   // RNE
  return (short)(r >> 16);
}
__device__ inline float bf2f(short s) {
  union { unsigned u; float f; } v; v.u = ((unsigned)(unsigned short)s) << 16;
  return v.f;
}

__device__ inline float blk_sum_(float x, float* buf, int nw) {
  const int lane = threadIdx.x & 63, w = threadIdx.x >> 6;
  #pragma unroll
  for (int m = 1; m < 64; m <<= 1) x += __shfl_xor(x, m, 64);
  __syncthreads();
  if (lane == 0) buf[w] = x;
  __syncthreads();
  float s = 0.f;
  for (int i = 0; i < nw; ++i) s += buf[i];
  return s;
}
__device__ inline float blk_max_(float x, float* buf, int nw) {
  const int lane = threadIdx.x & 63, w = threadIdx.x >> 6;
  #pragma unroll
  for (int m = 1; m < 64; m <<= 1) x = fmaxf(x, __shfl_xor(x, m, 64));
  __syncthreads();
  if (lane == 0) buf[w] = x;
  __syncthreads();
  float s = buf[0];
  for (int i = 1; i < nw; ++i) s = fmaxf(s, buf[i]);
  return s;
}

// ---------------- prep: 4 unit weights [512][512] fp32 -> fragment-major SWIZZLED bf16 ----
// chunk kc (32 k's): pos = n*32 + ((s ^ ((n>>1)&3))<<3) + j, where k%32 = s*8+j.
// XOR makes ds_read_b128 of B fragments bank-conflict-free while global_load_lds
// staging stays linear (swizzle baked into global layout, G21/m173).
__global__ __launch_bounds__(256) void k_cvt_frag4(
    const float* __restrict__ s0, const float* __restrict__ s1,
    const float* __restrict__ s2, const float* __restrict__ s3,
    short* __restrict__ d0, short* __restrict__ d1,
    short* __restrict__ d2, short* __restrict__ d3) {
  int m = blockIdx.x >> 10;
  const float* src = m == 0 ? s0 : m == 1 ? s1 : m == 2 ? s2 : s3;
  short* dst = m == 0 ? d0 : m == 1 ? d1 : m == 2 ? d2 : d3;
  int idx = (blockIdx.x & 1023) * 256 + threadIdx.x;   // k*512 + n (coalesced read)
  int k = idx >> 9, n = idx & 511;
  int kc = k >> 5, t = k & 31;
  int s = t >> 3, j = t & 7;
  int sw = (s ^ ((n >> 1) & 3)) << 3;
  dst[(size_t)kc * 16384 + n * 32 + sw + j] = f2bf(src[idx]);
}

// ---------------- prep: global-proj weights [K][512] -> [512][K] bf16 ----------------
__global__ __launch_bounds__(256) void k_transpose2(
    const float* __restrict__ gv, short* __restrict__ dv_,
    const float* __restrict__ gt, short* __restrict__ dt_) {
  int bid = blockIdx.x;
  if (bid < 1536) {
    int idx = bid * 256 + threadIdx.x;      // 768*512
    int k = idx >> 9, n = idx & 511;
    dv_[(size_t)n * 768 + k] = f2bf(gv[idx]);
  } else {
    int idx = (bid - 1536) * 256 + threadIdx.x;  // 512*512
    int k = idx >> 9, n = idx & 511;
    dt_[(size_t)n * 512 + k] = f2bf(gt[idx]);
  }
}

// ---------------- fused unit MLP: r7 structure + swizzled B + async-LDS staging ----------------
// 564 blocks: vis 256, txt 308. 1024 thr, 16 waves = 4rg x 4cg, wave = 16 rows x 128 cols.
// LDS: As 66560 + Bs dbuf 65536 + red 2048 = 134144 B (1 block/CU, 16 waves).
__global__ __launch_bounds__(1024) void k_unit_mlp10(
    const float* __restrict__ Xv, const float* __restrict__ Xt,
    const short* __restrict__ vWf1, const float* __restrict__ vb1,
    const float* __restrict__ vg, const float* __restrict__ vbt,
    const short* __restrict__ vWf2, const float* __restrict__ vb2,
    const short* __restrict__ tWf1, const float* __restrict__ tb1,
    const float* __restrict__ tg, const float* __restrict__ tbt,
    const short* __restrict__ tWf2, const float* __restrict__ tb2,
    float* __restrict__ outV, float* __restrict__ outT) {
  __shared__ __align__(16) short As[64][520];      // 66560 B (2-way A reads: free)
  __shared__ __align__(16) short Bs[2][16384];     // 65536 B dbuf, swizzled chunks
  __shared__ float redS[4][64];
  __shared__ float redQ[4][64];

  const int tid = threadIdx.x;
  const int w = tid >> 6, lane = tid & 63;
  const int rg = w >> 2, cg = w & 3;       // 4 row-groups (16 rows) x 4 col-groups (128 cols)
  const int hi = lane >> 4, lo = lane & 15;

  // bijective XCD swizzle for 564 = 8*70 + 4 (m204)
  const int xcd = blockIdx.x & 7, ii = blockIdx.x >> 3;
  const int orig = (xcd < 4 ? xcd * 71 : 284 + (xcd - 4) * 70) + ii;
  const bool isv = orig < 256;
  const int rb = isv ? orig : orig - 256;
  const float* __restrict__ X   = isv ? Xv : Xt;
  const short* __restrict__ Wf1 = isv ? vWf1 : tWf1;
  const float* __restrict__ b1  = isv ? vb1  : tb1;
  const float* __restrict__ gg  = isv ? vg   : tg;
  const float* __restrict__ bt  = isv ? vbt  : tbt;
  const short* __restrict__ Wf2 = isv ? vWf2 : tWf2;
  const float* __restrict__ b2  = isv ? vb2  : tb2;
  float* __restrict__ outF      = isv ? outV : outT;
  const size_t row0 = (size_t)rb * 64;

  const int arow = rg * 16 + lo;
  // conflict-free swizzled B-frag read base (matches baked weight swizzle)
  const int bswz = (cg * 128 + lo) * 32 + ((hi ^ ((lo >> 1) & 3)) * 8);

  // ---- issue W1 chunk 0 async into Bs[0] (no VGPR dest, not regalloc-sinkable) ----
  GL_LDS16(Wf1 + tid * 8, &Bs[0][tid * 8]);
  GL_LDS16(Wf1 + 8192 + tid * 8, &Bs[0][8192 + tid * 8]);

  // ---- stage X tile (64x512) -> As bf16 (coalesced, nontemporal) ----
  const f32x4* Xp = (const f32x4*)(X + row0 * 512);
  #pragma unroll
  for (int i = 0; i < 8; ++i) {
    int idx = i * 1024 + tid;                // 8192 f32x4 = 64 rows x 128
    f32x4 f = __builtin_nontemporal_load(Xp + idx);
    short4v s4 = {f2bf(f[0]), f2bf(f[1]), f2bf(f[2]), f2bf(f[3])};
    *(short4v*)&As[idx >> 7][(idx & 127) * 4] = s4;
  }
  __syncthreads();   // vmcnt(0) drained: X + W1 chunk 0 resident

  f32x4 acc[8];
  #pragma unroll
  for (int ct = 0; ct < 8; ++ct) acc[ct] = (f32x4){0.f, 0.f, 0.f, 0.f};

  // ---- GEMM1: compute Bs[kc&1]; async-prefetch next chunk (W2 chunk0 at kc=15) ----
  for (int kc = 0; kc < 16; ++kc) {
    const int cur = kc & 1;
    const short* nxt = (kc < 15) ? (Wf1 + (size_t)(kc + 1) * 16384) : Wf2;
    short* ldst = (kc < 15) ? &Bs[cur ^ 1][0] : &Bs[0][0];
    GL_LDS16(nxt + tid * 8, ldst + tid * 8);
    GL_LDS16(nxt + 8192 + tid * 8, ldst + 8192 + tid * 8);
    short8 a = *(const short8*)&As[arow][kc * 32 + hi * 8];
    #pragma unroll
    for (int ct = 0; ct < 8; ++ct) {
      short8 bb = *(const short8*)&Bs[cur][bswz + ct * 512];
      acc[ct] = __builtin_amdgcn_mfma_f32_16x16x32_bf16(a, bb, acc[ct], 0, 0, 0);
    }
    __syncthreads();   // vmcnt drain: next chunk resident; prev-buffer readers done
  }
  // Bs[0] holds W2 chunk 0

  // ---- bias + LN reduction ----
  {
    float ps[4] = {0.f, 0.f, 0.f, 0.f}, pq[4] = {0.f, 0.f, 0.f, 0.f};
    #pragma unroll
    for (int ct = 0; ct < 8; ++ct) {
      float bia = b1[cg * 128 + ct * 16 + lo];
      #pragma unroll
      for (int r = 0; r < 4; ++r) {
        float v = acc[ct][r] + bia;
        acc[ct][r] = v;
        ps[r] += v; pq[r] += v * v;
      }
    }
    #pragma unroll
    for (int m = 1; m < 16; m <<= 1)
      #pragma unroll
      for (int r = 0; r < 4; ++r) {
        ps[r] += __shfl_xor(ps[r], m, 64);
        pq[r] += __shfl_xor(pq[r], m, 64);
      }
    if (lo == 0) {
      #pragma unroll
      for (int r = 0; r < 4; ++r) {
        int rr = rg * 16 + hi * 4 + r;
        redS[cg][rr] = ps[r]; redQ[cg][rr] = pq[r];
      }
    }
  }
  __syncthreads();

  // ---- LN + GELU -> As (bf16 H tile) ----
  {
    float mu[4], rs[4];
    #pragma unroll
    for (int r = 0; r < 4; ++r) {
      int rr = rg * 16 + hi * 4 + r;
      float s = redS[0][rr] + redS[1][rr] + redS[2][rr] + redS[3][rr];
      float q = redQ[0][rr] + redQ[1][rr] + redQ[2][rr] + redQ[3][rr];
      float m_ = s * (1.f / 512.f);
      mu[r] = m_;
      rs[r] = rsqrtf(q * (1.f / 512.f) - m_ * m_ + 1e-5f);
    }
    #pragma unroll
    for (int ct = 0; ct < 8; ++ct) {
      int col = cg * 128 + ct * 16 + lo;
      float ga = gg[col], be = bt[col];
      #pragma unroll
      for (int r = 0; r < 4; ++r) {
        float xn = (acc[ct][r] - mu[r]) * rs[r] * ga + be;
        float ge = 0.5f * xn * (1.f + erff(xn * 0.70710678118654752f));
        As[rg * 16 + hi * 4 + r][col] = f2bf(ge);
      }
    }
  }
  __syncthreads();

  // ---- GEMM2 (W2 chunk 0 already resident in Bs[0]) ----
  #pragma unroll
  for (int ct = 0; ct < 8; ++ct) acc[ct] = (f32x4){0.f, 0.f, 0.f, 0.f};
  for (int kc = 0; kc < 16; ++kc) {
    const int cur = kc & 1;
    if (kc < 15) {
      const short* nxt = Wf2 + (size_t)(kc + 1) * 16384;
      GL_LDS16(nxt + tid * 8, &Bs[cur ^ 1][tid * 8]);
      GL_LDS16(nxt + 8192 + tid * 8, &Bs[cur ^ 1][8192 + tid * 8]);
    }
    short8 a = *(const short8*)&As[arow][kc * 32 + hi * 8];
    #pragma unroll
    for (int ct = 0; ct < 8; ++ct) {
      short8 bb = *(const short8*)&Bs[cur][bswz + ct * 512];
      acc[ct] = __builtin_amdgcn_mfma_f32_16x16x32_bf16(a, bb, acc[ct], 0, 0, 0);
    }
    __syncthreads();
  }

  // ---- bias2 + row L2 norm ----
  {
    float pq[4] = {0.f, 0.f, 0.f, 0.f};
    #pragma unroll
    for (int ct = 0; ct < 8; ++ct) {
      float bia = b2[cg * 128 + ct * 16 + lo];
      #pragma unroll
      for (int r = 0; r < 4; ++r) {
        float v = acc[ct][r] + bia;
        acc[ct][r] = v;
        pq[r] += v * v;
      }
    }
    #pragma unroll
    for (int m = 1; m < 16; m <<= 1)
      #pragma unroll
      for (int r = 0; r < 4; ++r) pq[r] += __shfl_xor(pq[r], m, 64);
    if (lo == 0) {
      #pragma unroll
      for (int r = 0; r < 4; ++r) redQ[cg][rg * 16 + hi * 4 + r] = pq[r];
    }
  }
  __syncthreads();
  {
    float invn[4];
    #pragma unroll
    for (int r = 0; r < 4; ++r) {
      int rr = rg * 16 + hi * 4 + r;
      float q = redQ[0][rr] + redQ[1][rr] + redQ[2][rr] + redQ[3][rr];
      invn[r] = 1.f / fmaxf(sqrtf(q), 1e-12f);
    }
    #pragma unroll
    for (int ct = 0; ct < 8; ++ct) {
      int col = cg * 128 + ct * 16 + lo;
      #pragma unroll
      for (int r = 0; r < 4; ++r)
        outF[(row0 + rg * 16 + hi * 4 + r) * 512 + col] = acc[ct][r] * invn[r];
    }
  }
}

// ---------------- global projections (both), Linear -> LN -> l2norm ----------------
__global__ __launch_bounds__(256) void k_gproj2(
    const float* __restrict__ vsrc, const float* __restrict__ tsrc,
    const short* __restrict__ vWT, const float* __restrict__ vbias,
    const float* __restrict__ vgg, const float* __restrict__ vbt,
    const short* __restrict__ tWT, const float* __restrict__ tbias,
    const float* __restrict__ tgg, const float* __restrict__ tbt,
    float* __restrict__ outV, float* __restrict__ outT) {
  __shared__ float srow[768];
  __shared__ float rbuf[4];
  const bool isv = blockIdx.x < 256;
  const int row = blockIdx.x & 255, tid = threadIdx.x;
  const int K = isv ? 768 : 512;
  const float* src = isv ? vsrc : tsrc;
  const short* WT = isv ? vWT : tWT;
  const float* bias = isv ? vbias : tbias;
  const float* gg = isv ? vgg : tgg;
  const float* bt = isv ? vbt : tbt;
  float* outp = isv ? outV : outT;

  for (int k = tid; k < K; k += 256) srow[k] = src[(size_t)row * K + k];
  __syncthreads();
  float v0 = 0.f, v1 = 0.f;
  const short* wp0 = WT + (size_t)tid * K;
  const short* wp1 = WT + (size_t)(tid + 256) * K;
  for (int k = 0; k < K; k += 8) {
    short8 wa = *(const short8*)(wp0 + k);
    short8 wb = *(const short8*)(wp1 + k);
    #pragma unroll
    for (int j = 0; j < 8; ++j) {
      float sv = srow[k + j];
      v0 += sv * bf2f(wa[j]);
      v1 += sv * bf2f(wb[j]);
    }
  }
  v0 += bias[tid]; v1 += bias[tid + 256];
  float s = blk_sum_(v0 + v1, rbuf, 4);
  float q = blk_sum_(v0 * v0 + v1 * v1, rbuf, 4);
  float mu = s * (1.f / 512.f);
  float var = q * (1.f / 512.f) - mu * mu;
  float rs = rsqrtf(var + 1e-5f);
  float y0 = (v0 - mu) * rs * gg[tid] + bt[tid];
  float y1 = (v1 - mu) * rs * gg[tid + 256] + bt[tid + 256];
  float ss = blk_sum_(y0 * y0 + y1 * y1, rbuf, 4);
  float invn = 1.f / fmaxf(sqrtf(ss), 1e-12f);
  outp[(size_t)row * 512 + tid] = y0 * invn;
  outp[(size_t)row * 512 + tid + 256] = y1 * invn;
}

// ---------------- logits rows ----------------
__global__ __launch_bounds__(256) void k_logits_row(
    const float* __restrict__ vgp, const float* __restrict__ tgp,
    const float* __restrict__ lsc, float* __restrict__ logits,
    float* __restrict__ diag, float* __restrict__ rlse) {
  __shared__ __align__(16) float vrow[512];
  __shared__ float rbuf[4];
  const int i = blockIdx.x, tid = threadIdx.x;
  const float scale = fminf(expf(lsc[0]), 100.f);
  vrow[tid] = vgp[(size_t)i * 512 + tid];
  vrow[tid + 256] = vgp[(size_t)i * 512 + 256 + tid];
  __syncthreads();
  const float4* tp4 = (const float4*)(tgp + (size_t)tid * 512);
  const float4* v4 = (const float4*)vrow;
  float s = 0.f;
  for (int k = 0; k < 128; ++k) {
    float4 t = tp4[k], vv = v4[k];
    s += t.x * vv.x + t.y * vv.y + t.z * vv.z + t.w * vv.w;
  }
  float lg = scale * s;
  logits[(size_t)i * 256 + tid] = lg;
  if (tid == i) diag[i] = lg;
  float mx = blk_max_(lg, rbuf, 4);
  float se = blk_sum_(expf(lg - mx), rbuf, 4);
  if (tid == 0) rlse[i] = mx + logf(se);
}

// ---------------- logits cols ----------------
__global__ __launch_bounds__(256) void k_logits_col(
    const float* __restrict__ logits, float* __restrict__ clse) {
  __shared__ float rbuf[4];
  const int j = blockIdx.x, tid = threadIdx.x;
  float lg = logits[(size_t)tid * 256 + j];
  float mx = blk_max_(lg, rbuf, 4);
  float se = blk_sum_(expf(lg - mx), rbuf, 4);
  if (tid == 0) clse[j] = mx + logf(se);
}

// ---------------- per-batch sim + mutual-NN unit loss (512 thr, K-split) ----------------
__global__ __launch_bounds__(512) void k_unit_sim(
    const float* __restrict__ vpp, const float* __restrict__ tpp,
    const float* __restrict__ lsc, float* __restrict__ simout,
    float* __restrict__ up, float* __restrict__ uc) {
  __shared__ float Sp[2][64][81];
  __shared__ float lse_r[64];
  __shared__ int bestt[64];
  __shared__ float lse_c[80];
  __shared__ int bestv[80];
  __shared__ float rbuf[8];
  const int b = blockIdx.x;
  const int tid = threadIdx.x;
  const int w = tid >> 6, lane = tid & 63;
  const int wq = w >> 1, kg = w & 1;       // v-row group, k-half
  const int hi = lane >> 4, lo = lane & 15;
  const float scale = fminf(expf(lsc[0]), 100.f);

  f32x4 acc[5];
  #pragma unroll
  for (int ct = 0; ct < 5; ++ct) acc[ct] = (f32x4){0.f, 0.f, 0.f, 0.f};

  const float* va = vpp + ((size_t)b * 64 + wq * 16 + lo) * 512 + kg * 256;
  const float* tbase = tpp + (size_t)b * 77 * 512 + kg * 256;
  for (int k0 = 0; k0 < 256; k0 += 32) {
    float4 f0 = *(const float4*)(va + k0 + hi * 8);
    float4 f1 = *(const float4*)(va + k0 + hi * 8 + 4);
    short8 a = {f2bf(f0.x), f2bf(f0.y), f2bf(f0.z), f2bf(f0.w),
                f2bf(f1.x), f2bf(f1.y), f2bf(f1.z), f2bf(f1.w)};
    #pragma unroll
    for (int ct = 0; ct < 5; ++ct) {
      int rj = ct * 16 + lo;
      short8 bb = {0, 0, 0, 0, 0, 0, 0, 0};
      if (rj < 77) {
        const float* tb = tbase + (size_t)rj * 512 + k0 + hi * 8;
        float4 g0 = *(const float4*)tb;
        float4 g1 = *(const float4*)(tb + 4);
        bb = (short8){f2bf(g0.x), f2bf(g0.y), f2bf(g0.z), f2bf(g0.w),
                      f2bf(g1.x), f2bf(g1.y), f2bf(g1.z), f2bf(g1.w)};
      }
      acc[ct] = __builtin_amdgcn_mfma_f32_16x16x32_bf16(a, bb, acc[ct], 0, 0, 0);
    }
  }
  #pragma unroll
  for (int ct = 0; ct < 5; ++ct)
    #pragma unroll
    for (int r = 0; r < 4; ++r) {
      int i = wq * 16 + hi * 4 + r, j = ct * 16 + lo;
      if (j < 77) Sp[kg][i][j] = acc[ct][r];
    }
  __syncthreads();
  for (int idx = tid; idx < 64 * 77; idx += 512) {
    int i = idx / 77, j = idx - i * 77;
    float s = Sp[0][i][j] + Sp[1][i][j];
    simout[((size_t)b * 64 + i) * 77 + j] = s;
    Sp[0][i][j] = s * scale;
  }
  __syncthreads();
  if (tid < 64) {
    float mx = -1e30f; int am = 0;
    for (int t = 0; t < 77; ++t) { float x = Sp[0][tid][t]; if (x > mx) { mx = x; am = t; } }
    float se = 0.f;
    for (int t = 0; t < 77; ++t) se += expf(Sp[0][tid][t] - mx);
    lse_r[tid] = mx + logf(se); bestt[tid] = am;
  } else if (tid < 64 + 77) {
    int t = tid - 64;
    float mx = -1e30f; int am = 0;
    for (int v = 0; v < 64; ++v) { float x = Sp[0][v][t]; if (x > mx) { mx = x; am = v; } }
    float se = 0.f;
    for (int v = 0; v < 64; ++v) se += expf(Sp[0][v][t] - mx);
    lse_c[t] = mx + logf(se); bestv[t] = am;
  }
  __syncthreads();
  float c = 0.f, cnt = 0.f;
  if (tid < 64) {
    int j = bestt[tid];
    if (bestv[j] == tid) {
      float sv = Sp[0][tid][j];
      c = -((sv - lse_r[tid]) + (sv - lse_c[j]));
      cnt = 2.f;
    }
  }
  c = blk_sum_(c, rbuf, 8);
  cnt = blk_sum_(cnt, rbuf, 8);
  if (tid == 0) { up[b] = c; uc[b] = cnt; }
}

// ---------------- fused diversity (both modalities): LDS-staged gram, norms from diag ----------------
__global__ __launch_bounds__(320) void k_div2(
    const float* __restrict__ Xv, const float* __restrict__ Xt,
    float* __restrict__ part) {
  __shared__ __align__(16) short Bsd[80][136];
  __shared__ float invs[80];
  __shared__ float rbuf[5];
  const int bid = blockIdx.x;
  const bool isv = bid < 256;
  const int b = bid & 255;
  const int N = isv ? 64 : 77;
  const float* X = (isv ? Xv : Xt) + (size_t)b * N * 512;
  const int w = threadIdx.x >> 6, lane = threadIdx.x & 63;
  const int hi = lane >> 4, lo = lane & 15;
  const int ri = w * 16 + lo;

  f32x4 acc[5];
  #pragma unroll
  for (int ct = 0; ct < 5; ++ct) acc[ct] = (f32x4){0.f, 0.f, 0.f, 0.f};

  for (int c = 0; c < 4; ++c) {
    for (int s = threadIdx.x; s < 80 * 32; s += 320) {
      int r = s >> 5, cgp = s & 31;
      short4v s4 = {0, 0, 0, 0};
      if (r < N) {
        float4 f = *(const float4*)(X + (size_t)r * 512 + c * 128 + cgp * 4);
        s4 = (short4v){f2bf(f.x), f2bf(f.y), f2bf(f.z), f2bf(f.w)};
      }
      *(short4v*)&Bsd[r][cgp * 4] = s4;
    }
    __syncthreads();
    #pragma unroll
    for (int kc = 0; kc < 4; ++kc) {
      short8 a = *(const short8*)&Bsd[ri][kc * 32 + hi * 8];
      #pragma unroll
      for (int ct = 0; ct < 5; ++ct) {
        short8 bb = *(const short8*)&Bsd[ct * 16 + lo][kc * 32 + hi * 8];
        acc[ct] = __builtin_amdgcn_mfma_f32_16x16x32_bf16(a, bb, acc[ct], 0, 0, 0);
      }
    }
    __syncthreads();
  }

  #pragma unroll
  for (int ct = 0; ct < 5; ++ct)
    #pragma unroll
    for (int r = 0; r < 4; ++r) {
      int i = w * 16 + hi * 4 + r, j = ct * 16 + lo;
      if (i == j && i < N) invs[i] = 1.f / fmaxf(sqrtf(fmaxf(acc[ct][r], 0.f)), 1e-12f);
    }
  __syncthreads();

  float cs = 0.f;
  #pragma unroll
  for (int ct = 0; ct < 5; ++ct)
    #pragma unroll
    for (int r = 0; r < 4; ++r) {
      int i = w * 16 + hi * 4 + r, j = ct * 16 + lo;
      if (i < N && j < N && i != j)
        cs += fabsf(acc[ct][r]) * invs[i] * invs[j];
    }
  #pragma unroll
  for (int m = 1; m < 64; m <<= 1) cs += __shfl_xor(cs, m, 64);
  if (lane == 0) rbuf[w] = cs;
  __syncthreads();
  if (threadIdx.x == 0) {
    float s = 0.f;
    for (int i = 0; i < 5; ++i) s += rbuf[i];
    part[bid] = s;
  }
}

// ---------------- final scalar losses ----------------
__global__ __launch_bounds__(256) void k_final(
    const float* __restrict__ diag, const float* __restrict__ rlse,
    const float* __restrict__ clse, const float* __restrict__ up,
    const float* __restrict__ uc, const float* __restrict__ part,
    float* __restrict__ out) {
  __shared__ float rbuf[4];
  const int tid = threadIdx.x;
  float d = diag[tid];
  float s1 = blk_sum_(d - rlse[tid], rbuf, 4);
  float s2 = blk_sum_(d - clse[tid], rbuf, 4);
  float su = blk_sum_(up[tid], rbuf, 4);
  float sc = blk_sum_(uc[tid], rbuf, 4);
  float sv = blk_sum_(part[tid], rbuf, 4);
  float st = blk_sum_(part[tid + 256], rbuf, 4);
  if (tid == 0) {
    out[0] = -(s1 * (1.f / 256.f) + s2 * (1.f / 256.f)) * 0.5f;
    out[1] = su / fmaxf(sc, 1.f);
    out[2] = (sv / (256.f * 64.f * 63.f) + st / (256.f * 77.f * 76.f)) * 0.5f;
  }
}

extern "C" void kernel_launch(void* const* d_in, const int* in_sizes, int n_in,
                              void* d_out, int out_size, void* d_ws, size_t ws_size,
                              hipStream_t stream) {
  const float* vis_units = (const float*)d_in[0];
  const float* txt_units = (const float*)d_in[1];
  const float* vis_cls = (const float*)d_in[2];
  const float* txt_cls = (const float*)d_in[3];
  const float* vW1 = (const float*)d_in[4];
  const float* vb1 = (const float*)d_in[5];
  const float* vg  = (const float*)d_in[6];
  const float* vbt = (const float*)d_in[7];
  const float* vW2 = (const float*)d_in[8];
  const float* vb2 = (const float*)d_in[9];
  const float* tW1 = (const float*)d_in[10];
  const float* tb1 = (const float*)d_in[11];
  const float* tg  = (const float*)d_in[12];
  const float* tbt = (const float*)d_in[13];
  const float* tW2 = (const float*)d_in[14];
  const float* tb2 = (const float*)d_in[15];
  const float* gvW = (const float*)d_in[16];
  const float* gvb = (const float*)d_in[17];
  const float* gvg = (const float*)d_in[18];
  const float* gvbt = (const float*)d_in[19];
  const float* gtW = (const float*)d_in[20];
  const float* gtb = (const float*)d_in[21];
  const float* gtg = (const float*)d_in[22];
  const float* gtbt = (const float*)d_in[23];
  const float* lsc = (const float*)d_in[24];

  float* out = (float*)d_out;
  char* ws = (char*)d_ws;
  short* vW1T = (short*)(ws + WS_VW1T);
  short* vW2T = (short*)(ws + WS_VW2T);
  short* tW1T = (short*)(ws + WS_TW1T);
  short* tW2T = (short*)(ws + WS_TW2T);
  short* gvWT = (short*)(ws + WS_GVWT);
  short* gtWT = (short*)(ws + WS_GTWT);
  float* logits = (float*)(ws + WS_LOG);
  float* diag = (float*)(ws + WS_DIAG);
  float* rlse = (float*)(ws + WS_RLSE);
  float* clse = (float*)(ws + WS_CLSE);
  float* up = (float*)(ws + WS_UP);
  float* uc = (float*)(ws + WS_UC);
  float* part = (float*)(ws + WS_PART);

  // prep (swizzle baked into unit-weight layout)
  k_cvt_frag4<<<4096, 256, 0, stream>>>(vW1, vW2, tW1, tW2, vW1T, vW2T, tW1T, tW2T);
  k_transpose2<<<2560, 256, 0, stream>>>(gvW, gvWT, gtW, gtWT);

  // unit MLPs (r7 structure + swizzled B + async staging)
  k_unit_mlp10<<<564, 1024, 0, stream>>>(
      vis_units, txt_units,
      vW1T, vb1, vg, vbt, vW2T, vb2,
      tW1T, tb1, tg, tbt, tW2T, tb2,
      out + O_VP, out + O_TP);

  // global projections
  k_gproj2<<<512, 256, 0, stream>>>(vis_cls, txt_cls,
      gvWT, gvb, gvg, gvbt, gtWT, gtb, gtg, gtbt,
      out + O_VG, out + O_TG);

  // global CLIP loss pieces
  k_logits_row<<<256, 256, 0, stream>>>(out + O_VG, out + O_TG, lsc, logits, diag, rlse);
  k_logits_col<<<256, 256, 0, stream>>>(logits, clse);

  // unit sim + mutual-NN loss partials (+ sim_matrix output)
  k_unit_sim<<<256, 512, 0, stream>>>(out + O_VP, out + O_TP, lsc, out + O_SM, up, uc);

  // diversity (both modalities)
  k_div2<<<512, 320, 0, stream>>>(vis_units, txt_units, part);

  // final scalars
  k_final<<<1, 256, 0, stream>>>(diag, rlse, clse, up, uc, part, out);

  (void)in_sizes; (void)n_in; (void)out_size; (void)ws_size;
}

// Round 15
// 257.856 us; speedup vs baseline: 1.4319x; 1.0647x over previous
//
#include <hip/hip_runtime.h>
#include <math.h>

typedef __attribute__((ext_vector_type(8))) short short8;
typedef __attribute__((ext_vector_type(4))) short short4v;
typedef __attribute__((ext_vector_type(4))) float f32x4;

#define NB 256
#define NVU 64
#define NTU 77
#define PD 512

// ---- d_out offsets (in floats) ----
#define O_VP 3ull
#define O_TP (O_VP + (size_t)NB * NVU * PD)
#define O_VG (O_TP + (size_t)NB * NTU * PD)
#define O_TG (O_VG + (size_t)NB * PD)
#define O_SM (O_TG + (size_t)NB * PD)

// ---- ws offsets (bytes) ----
#define WS_VW1T 0u
#define WS_VW2T 524288u
#define WS_TW1T 1048576u
#define WS_TW2T 1572864u
#define WS_GVWT 2097152u
#define WS_GTWT 2883584u
#define WS_LOG  3552256u
#define WS_DIAG 3814400u
#define WS_RLSE 3815424u
#define WS_CLSE 3816448u
#define WS_UP   3817472u
#define WS_UC   3818496u
#define WS_PART 3819520u   // 512 floats

// async global->LDS, 16B per lane; LDS dest = wave-uniform base + lane*16
#define GL_LDS16(gp, lp) __builtin_amdgcn_global_load_lds( \
    (const __attribute__((address_space(1))) void*)(gp), \
    (__attribute__((address_space(3))) void*)(lp), 16, 0, 0)

__device__ inline short f2bf(float f) {
  union { float f; unsigned u; } v; v.f = f;
  unsigned r = v.u + 0x7FFFu + ((v.u >> 16) & 1u);   // RNE
  return (short)(r >> 16);
}
__device__ inline float bf2f(short s) {
  union { unsigned u; float f; } v; v.u = ((unsigned)(unsigned short)s) << 16;
  return v.f;
}

__device__ inline float blk_sum_(float x, float* buf, int nw) {
  const int lane = threadIdx.x & 63, w = threadIdx.x >> 6;
  #pragma unroll
  for (int m = 1; m < 64; m <<= 1) x += __shfl_xor(x, m, 64);
  __syncthreads();
  if (lane == 0) buf[w] = x;
  __syncthreads();
  float s = 0.f;
  for (int i = 0; i < nw; ++i) s += buf[i];
  return s;
}
__device__ inline float blk_max_(float x, float* buf, int nw) {
  const int lane = threadIdx.x & 63, w = threadIdx.x >> 6;
  #pragma unroll
  for (int m = 1; m < 64; m <<= 1) x = fmaxf(x, __shfl_xor(x, m, 64));
  __syncthreads();
  if (lane == 0) buf[w] = x;
  __syncthreads();
  float s = buf[0];
  for (int i = 1; i < nw; ++i) s = fmaxf(s, buf[i]);
  return s;
}

// ---------------- prep: 4 unit weights [512][512] fp32 -> fragment-major SWIZZLED bf16 ----
// chunk kc (32 k's): pos = n*32 + ((s ^ ((n>>1)&3))<<3) + j, where k%32 = s*8+j.
__global__ __launch_bounds__(256) void k_cvt_frag4(
    const float* __restrict__ s0, const float* __restrict__ s1,
    const float* __restrict__ s2, const float* __restrict__ s3,
    short* __restrict__ d0, short* __restrict__ d1,
    short* __restrict__ d2, short* __restrict__ d3) {
  int m = blockIdx.x >> 10;
  const float* src = m == 0 ? s0 : m == 1 ? s1 : m == 2 ? s2 : s3;
  short* dst = m == 0 ? d0 : m == 1 ? d1 : m == 2 ? d2 : d3;
  int idx = (blockIdx.x & 1023) * 256 + threadIdx.x;   // k*512 + n (coalesced read)
  int k = idx >> 9, n = idx & 511;
  int kc = k >> 5, t = k & 31;
  int s = t >> 3, j = t & 7;
  int sw = (s ^ ((n >> 1) & 3)) << 3;
  dst[(size_t)kc * 16384 + n * 32 + sw + j] = f2bf(src[idx]);
}

// ---------------- prep: global-proj weights [K][512] -> [512][K] bf16 ----------------
__global__ __launch_bounds__(256) void k_transpose2(
    const float* __restrict__ gv, short* __restrict__ dv_,
    const float* __restrict__ gt, short* __restrict__ dt_) {
  int bid = blockIdx.x;
  if (bid < 1536) {
    int idx = bid * 256 + threadIdx.x;      // 768*512
    int k = idx >> 9, n = idx & 511;
    dv_[(size_t)n * 768 + k] = f2bf(gv[idx]);
  } else {
    int idx = (bid - 1536) * 256 + threadIdx.x;  // 512*512
    int k = idx >> 9, n = idx & 511;
    dt_[(size_t)n * 512 + k] = f2bf(gt[idx]);
  }
}

// ---------------- fused unit MLP: r14 + counted-vmcnt pipeline (T3/T4) ----------------
// 564 blocks: vis 256, txt 308. 1024 thr, 16 waves = 4rg x 4cg, wave = 16 rows x 128 cols.
__global__ __launch_bounds__(1024) void k_unit_mlp11(
    const float* __restrict__ Xv, const float* __restrict__ Xt,
    const short* __restrict__ vWf1, const float* __restrict__ vb1,
    const float* __restrict__ vg, const float* __restrict__ vbt,
    const short* __restrict__ vWf2, const float* __restrict__ vb2,
    const short* __restrict__ tWf1, const float* __restrict__ tb1,
    const float* __restrict__ tg, const float* __restrict__ tbt,
    const short* __restrict__ tWf2, const float* __restrict__ tb2,
    float* __restrict__ outV, float* __restrict__ outT) {
  __shared__ __align__(16) short As[64][520];      // 66560 B
  __shared__ __align__(16) short Bs[2][16384];     // 65536 B dbuf, swizzled chunks
  __shared__ float redS[4][64];
  __shared__ float redQ[4][64];

  const int tid = threadIdx.x;
  const int w = tid >> 6, lane = tid & 63;
  const int rg = w >> 2, cg = w & 3;
  const int hi = lane >> 4, lo = lane & 15;

  // bijective XCD swizzle for 564 = 8*70 + 4 (m204)
  const int xcd = blockIdx.x & 7, ii = blockIdx.x >> 3;
  const int orig = (xcd < 4 ? xcd * 71 : 284 + (xcd - 4) * 70) + ii;
  const bool isv = orig < 256;
  const int rb = isv ? orig : orig - 256;
  const float* __restrict__ X   = isv ? Xv : Xt;
  const short* __restrict__ Wf1 = isv ? vWf1 : tWf1;
  const float* __restrict__ b1  = isv ? vb1  : tb1;
  const float* __restrict__ gg  = isv ? vg   : tg;
  const float* __restrict__ bt  = isv ? vbt  : tbt;
  const short* __restrict__ Wf2 = isv ? vWf2 : tWf2;
  const float* __restrict__ b2  = isv ? vb2  : tb2;
  float* __restrict__ outF      = isv ? outV : outT;
  const size_t row0 = (size_t)rb * 64;

  const int arow = rg * 16 + lo;
  const int bswz = (cg * 128 + lo) * 32 + ((hi ^ ((lo >> 1) & 3)) * 8);

  // ---- issue W1 chunk 0 async into Bs[0] ----
  GL_LDS16(Wf1 + tid * 8, &Bs[0][tid * 8]);
  GL_LDS16(Wf1 + 8192 + tid * 8, &Bs[0][8192 + tid * 8]);

  // ---- stage X tile (64x512) -> As bf16 (coalesced, nontemporal) ----
  const f32x4* Xp = (const f32x4*)(X + row0 * 512);
  #pragma unroll
  for (int i = 0; i < 8; ++i) {
    int idx = i * 1024 + tid;
    f32x4 f = __builtin_nontemporal_load(Xp + idx);
    short4v s4 = {f2bf(f[0]), f2bf(f[1]), f2bf(f[2]), f2bf(f[3])};
    *(short4v*)&As[idx >> 7][(idx & 127) * 4] = s4;
  }
  __syncthreads();   // full drain: X + W1 chunk 0 resident, vmcnt=0 baseline

  f32x4 acc[8];
  #pragma unroll
  for (int ct = 0; ct < 8; ++ct) acc[ct] = (f32x4){0.f, 0.f, 0.f, 0.f};

  // issue W1 chunk 1 into Bs[1] (2 in flight)
  GL_LDS16(Wf1 + 16384 + tid * 8, &Bs[1][tid * 8]);
  GL_LDS16(Wf1 + 16384 + 8192 + tid * 8, &Bs[1][8192 + tid * 8]);

  // ---- GEMM1: compute chunk kc from Bs[kc&1]; barrier; issue kc+2 into freed buf;
  //      counted vmcnt(2) confirms kc+1 arrived (kc+2 stays in flight) ----
  for (int kc = 0; kc < 16; ++kc) {
    const int cur = kc & 1;
    short8 a = *(const short8*)&As[arow][kc * 32 + hi * 8];
    #pragma unroll
    for (int ct = 0; ct < 8; ++ct) {
      short8 bb = *(const short8*)&Bs[cur][bswz + ct * 512];
      acc[ct] = __builtin_amdgcn_mfma_f32_16x16x32_bf16(a, bb, acc[ct], 0, 0, 0);
    }
    __builtin_amdgcn_s_barrier();            // all waves done reading buf[cur]
    // issue chunk kc+2 (W1 chunks 2..15, then W2 chunks 0..1) into buf[cur]
    const int nc = kc + 2;
    const short* nxt = (nc < 16) ? (Wf1 + (size_t)nc * 16384)
                                 : (Wf2 + (size_t)(nc - 16) * 16384);
    GL_LDS16(nxt + tid * 8, &Bs[cur][tid * 8]);
    GL_LDS16(nxt + 8192 + tid * 8, &Bs[cur][8192 + tid * 8]);
    asm volatile("s_waitcnt vmcnt(2)" ::: "memory");   // chunk kc+1 resident
  }
  // state: W2 chunk0 resident in Bs[0]; W2 chunk1 in flight into Bs[1]

  // ---- bias + LN reduction ----
  {
    float ps[4] = {0.f, 0.f, 0.f, 0.f}, pq[4] = {0.f, 0.f, 0.f, 0.f};
    #pragma unroll
    for (int ct = 0; ct < 8; ++ct) {
      float bia = b1[cg * 128 + ct * 16 + lo];
      #pragma unroll
      for (int r = 0; r < 4; ++r) {
        float v = acc[ct][r] + bia;
        acc[ct][r] = v;
        ps[r] += v; pq[r] += v * v;
      }
    }
    #pragma unroll
    for (int m = 1; m < 16; m <<= 1)
      #pragma unroll
      for (int r = 0; r < 4; ++r) {
        ps[r] += __shfl_xor(ps[r], m, 64);
        pq[r] += __shfl_xor(pq[r], m, 64);
      }
    if (lo == 0) {
      #pragma unroll
      for (int r = 0; r < 4; ++r) {
        int rr = rg * 16 + hi * 4 + r;
        redS[cg][rr] = ps[r]; redQ[cg][rr] = pq[r];
      }
    }
  }
  __syncthreads();   // full drain: W2 chunk1 completes here too

  // ---- LN + GELU -> As (bf16 H tile) ----
  {
    float mu[4], rs[4];
    #pragma unroll
    for (int r = 0; r < 4; ++r) {
      int rr = rg * 16 + hi * 4 + r;
      float s = redS[0][rr] + redS[1][rr] + redS[2][rr] + redS[3][rr];
      float q = redQ[0][rr] + redQ[1][rr] + redQ[2][rr] + redQ[3][rr];
      float m_ = s * (1.f / 512.f);
      mu[r] = m_;
      rs[r] = rsqrtf(q * (1.f / 512.f) - m_ * m_ + 1e-5f);
    }
    #pragma unroll
    for (int ct = 0; ct < 8; ++ct) {
      int col = cg * 128 + ct * 16 + lo;
      float ga = gg[col], be = bt[col];
      #pragma unroll
      for (int r = 0; r < 4; ++r) {
        float xn = (acc[ct][r] - mu[r]) * rs[r] * ga + be;
        float ge = 0.5f * xn * (1.f + erff(xn * 0.70710678118654752f));
        As[rg * 16 + hi * 4 + r][col] = f2bf(ge);
      }
    }
  }
  __syncthreads();   // H tile ready; W2 chunks 0,1 both resident, vmcnt=0

  // ---- GEMM2: same counted pipeline over W2 chunks ----
  #pragma unroll
  for (int ct = 0; ct < 8; ++ct) acc[ct] = (f32x4){0.f, 0.f, 0.f, 0.f};
  for (int kc = 0; kc < 16; ++kc) {
    const int cur = kc & 1;
    short8 a = *(const short8*)&As[arow][kc * 32 + hi * 8];
    #pragma unroll
    for (int ct = 0; ct < 8; ++ct) {
      short8 bb = *(const short8*)&Bs[cur][bswz + ct * 512];
      acc[ct] = __builtin_amdgcn_mfma_f32_16x16x32_bf16(a, bb, acc[ct], 0, 0, 0);
    }
    __builtin_amdgcn_s_barrier();
    if (kc < 14) {
      const short* nxt = Wf2 + (size_t)(kc + 2) * 16384;
      GL_LDS16(nxt + tid * 8, &Bs[cur][tid * 8]);
      GL_LDS16(nxt + 8192 + tid * 8, &Bs[cur][8192 + tid * 8]);
      asm volatile("s_waitcnt vmcnt(2)" ::: "memory");
    } else if (kc == 14) {
      asm volatile("s_waitcnt vmcnt(0)" ::: "memory");   // chunk 15 resident
    }
  }

  // ---- bias2 + row L2 norm ----
  {
    float pq[4] = {0.f, 0.f, 0.f, 0.f};
    #pragma unroll
    for (int ct = 0; ct < 8; ++ct) {
      float bia = b2[cg * 128 + ct * 16 + lo];
      #pragma unroll
      for (int r = 0; r < 4; ++r) {
        float v = acc[ct][r] + bia;
        acc[ct][r] = v;
        pq[r] += v * v;
      }
    }
    #pragma unroll
    for (int m = 1; m < 16; m <<= 1)
      #pragma unroll
      for (int r = 0; r < 4; ++r) pq[r] += __shfl_xor(pq[r], m, 64);
    if (lo == 0) {
      #pragma unroll
      for (int r = 0; r < 4; ++r) redQ[cg][rg * 16 + hi * 4 + r] = pq[r];
    }
  }
  __syncthreads();
  {
    float invn[4];
    #pragma unroll
    for (int r = 0; r < 4; ++r) {
      int rr = rg * 16 + hi * 4 + r;
      float q = redQ[0][rr] + redQ[1][rr] + redQ[2][rr] + redQ[3][rr];
      invn[r] = 1.f / fmaxf(sqrtf(q), 1e-12f);
    }
    #pragma unroll
    for (int ct = 0; ct < 8; ++ct) {
      int col = cg * 128 + ct * 16 + lo;
      #pragma unroll
      for (int r = 0; r < 4; ++r)
        outF[(row0 + rg * 16 + hi * 4 + r) * 512 + col] = acc[ct][r] * invn[r];
    }
  }
}

// ---------------- global projections (both), Linear -> LN -> l2norm ----------------
__global__ __launch_bounds__(256) void k_gproj2(
    const float* __restrict__ vsrc, const float* __restrict__ tsrc,
    const short* __restrict__ vWT, const float* __restrict__ vbias,
    const float* __restrict__ vgg, const float* __restrict__ vbt,
    const short* __restrict__ tWT, const float* __restrict__ tbias,
    const float* __restrict__ tgg, const float* __restrict__ tbt,
    float* __restrict__ outV, float* __restrict__ outT) {
  __shared__ float srow[768];
  __shared__ float rbuf[4];
  const bool isv = blockIdx.x < 256;
  const int row = blockIdx.x & 255, tid = threadIdx.x;
  const int K = isv ? 768 : 512;
  const float* src = isv ? vsrc : tsrc;
  const short* WT = isv ? vWT : tWT;
  const float* bias = isv ? vbias : tbias;
  const float* gg = isv ? vgg : tgg;
  const float* bt = isv ? vbt : tbt;
  float* outp = isv ? outV : outT;

  for (int k = tid; k < K; k += 256) srow[k] = src[(size_t)row * K + k];
  __syncthreads();
  float v0 = 0.f, v1 = 0.f;
  const short* wp0 = WT + (size_t)tid * K;
  const short* wp1 = WT + (size_t)(tid + 256) * K;
  for (int k = 0; k < K; k += 8) {
    short8 wa = *(const short8*)(wp0 + k);
    short8 wb = *(const short8*)(wp1 + k);
    #pragma unroll
    for (int j = 0; j < 8; ++j) {
      float sv = srow[k + j];
      v0 += sv * bf2f(wa[j]);
      v1 += sv * bf2f(wb[j]);
    }
  }
  v0 += bias[tid]; v1 += bias[tid + 256];
  float s = blk_sum_(v0 + v1, rbuf, 4);
  float q = blk_sum_(v0 * v0 + v1 * v1, rbuf, 4);
  float mu = s * (1.f / 512.f);
  float var = q * (1.f / 512.f) - mu * mu;
  float rs = rsqrtf(var + 1e-5f);
  float y0 = (v0 - mu) * rs * gg[tid] + bt[tid];
  float y1 = (v1 - mu) * rs * gg[tid + 256] + bt[tid + 256];
  float ss = blk_sum_(y0 * y0 + y1 * y1, rbuf, 4);
  float invn = 1.f / fmaxf(sqrtf(ss), 1e-12f);
  outp[(size_t)row * 512 + tid] = y0 * invn;
  outp[(size_t)row * 512 + tid + 256] = y1 * invn;
}

// ---------------- logits rows ----------------
__global__ __launch_bounds__(256) void k_logits_row(
    const float* __restrict__ vgp, const float* __restrict__ tgp,
    const float* __restrict__ lsc, float* __restrict__ logits,
    float* __restrict__ diag, float* __restrict__ rlse) {
  __shared__ __align__(16) float vrow[512];
  __shared__ float rbuf[4];
  const int i = blockIdx.x, tid = threadIdx.x;
  const float scale = fminf(expf(lsc[0]), 100.f);
  vrow[tid] = vgp[(size_t)i * 512 + tid];
  vrow[tid + 256] = vgp[(size_t)i * 512 + 256 + tid];
  __syncthreads();
  const float4* tp4 = (const float4*)(tgp + (size_t)tid * 512);
  const float4* v4 = (const float4*)vrow;
  float s = 0.f;
  for (int k = 0; k < 128; ++k) {
    float4 t = tp4[k], vv = v4[k];
    s += t.x * vv.x + t.y * vv.y + t.z * vv.z + t.w * vv.w;
  }
  float lg = scale * s;
  logits[(size_t)i * 256 + tid] = lg;
  if (tid == i) diag[i] = lg;
  float mx = blk_max_(lg, rbuf, 4);
  float se = blk_sum_(expf(lg - mx), rbuf, 4);
  if (tid == 0) rlse[i] = mx + logf(se);
}

// ---------------- logits cols ----------------
__global__ __launch_bounds__(256) void k_logits_col(
    const float* __restrict__ logits, float* __restrict__ clse) {
  __shared__ float rbuf[4];
  const int j = blockIdx.x, tid = threadIdx.x;
  float lg = logits[(size_t)tid * 256 + j];
  float mx = blk_max_(lg, rbuf, 4);
  float se = blk_sum_(expf(lg - mx), rbuf, 4);
  if (tid == 0) clse[j] = mx + logf(se);
}

// ---------------- per-batch sim + mutual-NN unit loss (512 thr, K-split) ----------------
__global__ __launch_bounds__(512) void k_unit_sim(
    const float* __restrict__ vpp, const float* __restrict__ tpp,
    const float* __restrict__ lsc, float* __restrict__ simout,
    float* __restrict__ up, float* __restrict__ uc) {
  __shared__ float Sp[2][64][81];
  __shared__ float lse_r[64];
  __shared__ int bestt[64];
  __shared__ float lse_c[80];
  __shared__ int bestv[80];
  __shared__ float rbuf[8];
  const int b = blockIdx.x;
  const int tid = threadIdx.x;
  const int w = tid >> 6, lane = tid & 63;
  const int wq = w >> 1, kg = w & 1;
  const int hi = lane >> 4, lo = lane & 15;
  const float scale = fminf(expf(lsc[0]), 100.f);

  f32x4 acc[5];
  #pragma unroll
  for (int ct = 0; ct < 5; ++ct) acc[ct] = (f32x4){0.f, 0.f, 0.f, 0.f};

  const float* va = vpp + ((size_t)b * 64 + wq * 16 + lo) * 512 + kg * 256;
  const float* tbase = tpp + (size_t)b * 77 * 512 + kg * 256;
  for (int k0 = 0; k0 < 256; k0 += 32) {
    float4 f0 = *(const float4*)(va + k0 + hi * 8);
    float4 f1 = *(const float4*)(va + k0 + hi * 8 + 4);
    short8 a = {f2bf(f0.x), f2bf(f0.y), f2bf(f0.z), f2bf(f0.w),
                f2bf(f1.x), f2bf(f1.y), f2bf(f1.z), f2bf(f1.w)};
    #pragma unroll
    for (int ct = 0; ct < 5; ++ct) {
      int rj = ct * 16 + lo;
      short8 bb = {0, 0, 0, 0, 0, 0, 0, 0};
      if (rj < 77) {
        const float* tb = tbase + (size_t)rj * 512 + k0 + hi * 8;
        float4 g0 = *(const float4*)tb;
        float4 g1 = *(const float4*)(tb + 4);
        bb = (short8){f2bf(g0.x), f2bf(g0.y), f2bf(g0.z), f2bf(g0.w),
                      f2bf(g1.x), f2bf(g1.y), f2bf(g1.z), f2bf(g1.w)};
      }
      acc[ct] = __builtin_amdgcn_mfma_f32_16x16x32_bf16(a, bb, acc[ct], 0, 0, 0);
    }
  }
  #pragma unroll
  for (int ct = 0; ct < 5; ++ct)
    #pragma unroll
    for (int r = 0; r < 4; ++r) {
      int i = wq * 16 + hi * 4 + r, j = ct * 16 + lo;
      if (j < 77) Sp[kg][i][j] = acc[ct][r];
    }
  __syncthreads();
  for (int idx = tid; idx < 64 * 77; idx += 512) {
    int i = idx / 77, j = idx - i * 77;
    float s = Sp[0][i][j] + Sp[1][i][j];
    simout[((size_t)b * 64 + i) * 77 + j] = s;
    Sp[0][i][j] = s * scale;
  }
  __syncthreads();
  if (tid < 64) {
    float mx = -1e30f; int am = 0;
    for (int t = 0; t < 77; ++t) { float x = Sp[0][tid][t]; if (x > mx) { mx = x; am = t; } }
    float se = 0.f;
    for (int t = 0; t < 77; ++t) se += expf(Sp[0][tid][t] - mx);
    lse_r[tid] = mx + logf(se); bestt[tid] = am;
  } else if (tid < 64 + 77) {
    int t = tid - 64;
    float mx = -1e30f; int am = 0;
    for (int v = 0; v < 64; ++v) { float x = Sp[0][v][t]; if (x > mx) { mx = x; am = v; } }
    float se = 0.f;
    for (int v = 0; v < 64; ++v) se += expf(Sp[0][v][t] - mx);
    lse_c[t] = mx + logf(se); bestv[t] = am;
  }
  __syncthreads();
  float c = 0.f, cnt = 0.f;
  if (tid < 64) {
    int j = bestt[tid];
    if (bestv[j] == tid) {
      float sv = Sp[0][tid][j];
      c = -((sv - lse_r[tid]) + (sv - lse_c[j]));
      cnt = 2.f;
    }
  }
  c = blk_sum_(c, rbuf, 8);
  cnt = blk_sum_(cnt, rbuf, 8);
  if (tid == 0) { up[b] = c; uc[b] = cnt; }
}

// ---------------- fused diversity (both modalities): LDS-staged gram, norms from diag ----------------
__global__ __launch_bounds__(320) void k_div2(
    const float* __restrict__ Xv, const float* __restrict__ Xt,
    float* __restrict__ part) {
  __shared__ __align__(16) short Bsd[80][136];
  __shared__ float invs[80];
  __shared__ float rbuf[5];
  const int bid = blockIdx.x;
  const bool isv = bid < 256;
  const int b = bid & 255;
  const int N = isv ? 64 : 77;
  const float* X = (isv ? Xv : Xt) + (size_t)b * N * 512;
  const int w = threadIdx.x >> 6, lane = threadIdx.x & 63;
  const int hi = lane >> 4, lo = lane & 15;
  const int ri = w * 16 + lo;

  f32x4 acc[5];
  #pragma unroll
  for (int ct = 0; ct < 5; ++ct) acc[ct] = (f32x4){0.f, 0.f, 0.f, 0.f};

  for (int c = 0; c < 4; ++c) {
    for (int s = threadIdx.x; s < 80 * 32; s += 320) {
      int r = s >> 5, cgp = s & 31;
      short4v s4 = {0, 0, 0, 0};
      if (r < N) {
        float4 f = *(const float4*)(X + (size_t)r * 512 + c * 128 + cgp * 4);
        s4 = (short4v){f2bf(f.x), f2bf(f.y), f2bf(f.z), f2bf(f.w)};
      }
      *(short4v*)&Bsd[r][cgp * 4] = s4;
    }
    __syncthreads();
    #pragma unroll
    for (int kc = 0; kc < 4; ++kc) {
      short8 a = *(const short8*)&Bsd[ri][kc * 32 + hi * 8];
      #pragma unroll
      for (int ct = 0; ct < 5; ++ct) {
        short8 bb = *(const short8*)&Bsd[ct * 16 + lo][kc * 32 + hi * 8];
        acc[ct] = __builtin_amdgcn_mfma_f32_16x16x32_bf16(a, bb, acc[ct], 0, 0, 0);
      }
    }
    __syncthreads();
  }

  #pragma unroll
  for (int ct = 0; ct < 5; ++ct)
    #pragma unroll
    for (int r = 0; r < 4; ++r) {
      int i = w * 16 + hi * 4 + r, j = ct * 16 + lo;
      if (i == j && i < N) invs[i] = 1.f / fmaxf(sqrtf(fmaxf(acc[ct][r], 0.f)), 1e-12f);
    }
  __syncthreads();

  float cs = 0.f;
  #pragma unroll
  for (int ct = 0; ct < 5; ++ct)
    #pragma unroll
    for (int r = 0; r < 4; ++r) {
      int i = w * 16 + hi * 4 + r, j = ct * 16 + lo;
      if (i < N && j < N && i != j)
        cs += fabsf(acc[ct][r]) * invs[i] * invs[j];
    }
  #pragma unroll
  for (int m = 1; m < 64; m <<= 1) cs += __shfl_xor(cs, m, 64);
  if (lane == 0) rbuf[w] = cs;
  __syncthreads();
  if (threadIdx.x == 0) {
    float s = 0.f;
    for (int i = 0; i < 5; ++i) s += rbuf[i];
    part[bid] = s;
  }
}

// ---------------- final scalar losses ----------------
__global__ __launch_bounds__(256) void k_final(
    const float* __restrict__ diag, const float* __restrict__ rlse,
    const float* __restrict__ clse, const float* __restrict__ up,
    const float* __restrict__ uc, const float* __restrict__ part,
    float* __restrict__ out) {
  __shared__ float rbuf[4];
  const int tid = threadIdx.x;
  float d = diag[tid];
  float s1 = blk_sum_(d - rlse[tid], rbuf, 4);
  float s2 = blk_sum_(d - clse[tid], rbuf, 4);
  float su = blk_sum_(up[tid], rbuf, 4);
  float sc = blk_sum_(uc[tid], rbuf, 4);
  float sv = blk_sum_(part[tid], rbuf, 4);
  float st = blk_sum_(part[tid + 256], rbuf, 4);
  if (tid == 0) {
    out[0] = -(s1 * (1.f / 256.f) + s2 * (1.f / 256.f)) * 0.5f;
    out[1] = su / fmaxf(sc, 1.f);
    out[2] = (sv / (256.f * 64.f * 63.f) + st / (256.f * 77.f * 76.f)) * 0.5f;
  }
}

extern "C" void kernel_launch(void* const* d_in, const int* in_sizes, int n_in,
                              void* d_out, int out_size, void* d_ws, size_t ws_size,
                              hipStream_t stream) {
  const float* vis_units = (const float*)d_in[0];
  const float* txt_units = (const float*)d_in[1];
  const float* vis_cls = (const float*)d_in[2];
  const float* txt_cls = (const float*)d_in[3];
  const float* vW1 = (const float*)d_in[4];
  const float* vb1 = (const float*)d_in[5];
  const float* vg  = (const float*)d_in[6];
  const float* vbt = (const float*)d_in[7];
  const float* vW2 = (const float*)d_in[8];
  const float* vb2 = (const float*)d_in[9];
  const float* tW1 = (const float*)d_in[10];
  const float* tb1 = (const float*)d_in[11];
  const float* tg  = (const float*)d_in[12];
  const float* tbt = (const float*)d_in[13];
  const float* tW2 = (const float*)d_in[14];
  const float* tb2 = (const float*)d_in[15];
  const float* gvW = (const float*)d_in[16];
  const float* gvb = (const float*)d_in[17];
  const float* gvg = (const float*)d_in[18];
  const float* gvbt = (const float*)d_in[19];
  const float* gtW = (const float*)d_in[20];
  const float* gtb = (const float*)d_in[21];
  const float* gtg = (const float*)d_in[22];
  const float* gtbt = (const float*)d_in[23];
  const float* lsc = (const float*)d_in[24];

  float* out = (float*)d_out;
  char* ws = (char*)d_ws;
  short* vW1T = (short*)(ws + WS_VW1T);
  short* vW2T = (short*)(ws + WS_VW2T);
  short* tW1T = (short*)(ws + WS_TW1T);
  short* tW2T = (short*)(ws + WS_TW2T);
  short* gvWT = (short*)(ws + WS_GVWT);
  short* gtWT = (short*)(ws + WS_GTWT);
  float* logits = (float*)(ws + WS_LOG);
  float* diag = (float*)(ws + WS_DIAG);
  float* rlse = (float*)(ws + WS_RLSE);
  float* clse = (float*)(ws + WS_CLSE);
  float* up = (float*)(ws + WS_UP);
  float* uc = (float*)(ws + WS_UC);
  float* part = (float*)(ws + WS_PART);

  // prep (swizzle baked into unit-weight layout)
  k_cvt_frag4<<<4096, 256, 0, stream>>>(vW1, vW2, tW1, tW2, vW1T, vW2T, tW1T, tW2T);
  k_transpose2<<<2560, 256, 0, stream>>>(gvW, gvWT, gtW, gtWT);

  // unit MLPs (r14 + counted-vmcnt pipeline)
  k_unit_mlp11<<<564, 1024, 0, stream>>>(
      vis_units, txt_units,
      vW1T, vb1, vg, vbt, vW2T, vb2,
      tW1T, tb1, tg, tbt, tW2T, tb2,
      out + O_VP, out + O_TP);

  // global projections
  k_gproj2<<<512, 256, 0, stream>>>(vis_cls, txt_cls,
      gvWT, gvb, gvg, gvbt, gtWT, gtb, gtg, gtbt,
      out + O_VG, out + O_TG);

  // global CLIP loss pieces
  k_logits_row<<<256, 256, 0, stream>>>(out + O_VG, out + O_TG, lsc, logits, diag, rlse);
  k_logits_col<<<256, 256, 0, stream>>>(logits, clse);

  // unit sim + mutual-NN loss partials (+ sim_matrix output)
  k_unit_sim<<<256, 512, 0, stream>>>(out + O_VP, out + O_TP, lsc, out + O_SM, up, uc);

  // diversity (both modalities)
  k_div2<<<512, 320, 0, stream>>>(vis_units, txt_units, part);

  // final scalars
  k_final<<<1, 256, 0, stream>>>(diag, rlse, clse, up, uc, part, out);

  (void)in_sizes; (void)n_in; (void)out_size; (void)ws_size;
}